// Round 1
// baseline (420.723 us; speedup 1.0000x reference)
//
#include <hip/hip_runtime.h>
#include <hip/hip_bf16.h>

typedef unsigned short u16;
typedef __bf16 bf16x8 __attribute__((ext_vector_type(8)));
typedef float f32x4 __attribute__((ext_vector_type(4)));

#define SEQ 2048
#define DMODEL 512
#define NHEAD 8
#define DFF 2048
#define NBATCH 8
#define MROWS (NBATCH * SEQ)

__device__ __forceinline__ u16 f2b(float f) {
    __hip_bfloat16 h = __float2bfloat16(f);
    u16 u;
    __builtin_memcpy(&u, &h, 2);
    return u;
}

// async global->LDS, 16B per lane. LDS dest must be wave-uniform base; lane i
// lands at base + i*16. Address-space casts via uintptr_t (CK pattern).
__device__ __forceinline__ void gload_lds16(const void* g, void* lds) {
    auto* gp = reinterpret_cast<const __attribute__((address_space(1))) unsigned int*>(
        reinterpret_cast<uintptr_t>(g));
    auto* lp = reinterpret_cast<__attribute__((address_space(3))) unsigned int*>(
        reinterpret_cast<uintptr_t>(lds));
    __builtin_amdgcn_global_load_lds(gp, lp, 16, 0, 0);
}

// ---------------------------------------------------------------------------
// Weight cast fp32 -> bf16 (6 matrices in one launch).
// grid: 4*128 + 512 + 512 = 1536 blocks, 256 threads, 8 elems/thread.
// ---------------------------------------------------------------------------
__global__ __launch_bounds__(256) void cast_weights(
    const float* __restrict__ w0, const float* __restrict__ w1,
    const float* __restrict__ w2, const float* __restrict__ w3,
    const float* __restrict__ w4, const float* __restrict__ w5,
    u16* __restrict__ d0, u16* __restrict__ d1, u16* __restrict__ d2,
    u16* __restrict__ d3, u16* __restrict__ d4, u16* __restrict__ d5) {
    int blk = blockIdx.x;
    const float* s;
    u16* d;
    int base;
    if (blk < 512) {
        int seg = blk >> 7, lb = blk & 127;
        s = seg == 0 ? w0 : seg == 1 ? w1 : seg == 2 ? w2 : w3;
        d = seg == 0 ? d0 : seg == 1 ? d1 : seg == 2 ? d2 : d3;
        base = lb * 2048;
    } else if (blk < 1024) {
        s = w4; d = d4; base = (blk - 512) * 2048;
    } else {
        s = w5; d = d5; base = (blk - 1024) * 2048;
    }
    int i = base + threadIdx.x * 8;
    float4 a = *reinterpret_cast<const float4*>(s + i);
    float4 b = *reinterpret_cast<const float4*>(s + i + 4);
    ushort4 oa, ob;
    oa.x = f2b(a.x); oa.y = f2b(a.y); oa.z = f2b(a.z); oa.w = f2b(a.w);
    ob.x = f2b(b.x); ob.y = f2b(b.y); ob.z = f2b(b.z); ob.w = f2b(b.w);
    *reinterpret_cast<ushort4*>(d + i) = oa;
    *reinterpret_cast<ushort4*>(d + i + 4) = ob;
}

// ---------------------------------------------------------------------------
// LayerNorm (unbiased var, ddof=1; eps inside sqrt), fp32 in -> bf16 out.
// One wave per 512-elem row; 4 rows per block; grid = 4096.
// ---------------------------------------------------------------------------
__global__ __launch_bounds__(256) void ln_rows(const float* __restrict__ x,
                                               u16* __restrict__ out) {
    int row = blockIdx.x * 4 + (threadIdx.x >> 6);
    int l = threadIdx.x & 63;
    const float* xr = x + (size_t)row * DMODEL + l * 8;
    float4 a = *reinterpret_cast<const float4*>(xr);
    float4 b = *reinterpret_cast<const float4*>(xr + 4);
    float s = a.x + a.y + a.z + a.w + b.x + b.y + b.z + b.w;
    float q = a.x * a.x + a.y * a.y + a.z * a.z + a.w * a.w +
              b.x * b.x + b.y * b.y + b.z * b.z + b.w * b.w;
#pragma unroll
    for (int d = 32; d >= 1; d >>= 1) {
        s += __shfl_xor(s, d, 64);
        q += __shfl_xor(q, d, 64);
    }
    float mean = s * (1.f / 512.f);
    float var = (q - 512.f * mean * mean) * (1.f / 511.f);
    float rs = rsqrtf(var + 1e-6f);
    ushort4 o0, o1;
    o0.x = f2b((a.x - mean) * rs); o0.y = f2b((a.y - mean) * rs);
    o0.z = f2b((a.z - mean) * rs); o0.w = f2b((a.w - mean) * rs);
    o1.x = f2b((b.x - mean) * rs); o1.y = f2b((b.y - mean) * rs);
    o1.z = f2b((b.z - mean) * rs); o1.w = f2b((b.w - mean) * rs);
    u16* op = out + (size_t)row * DMODEL + l * 8;
    *reinterpret_cast<ushort4*>(op) = o0;
    *reinterpret_cast<ushort4*>(op + 4) = o1;
}

// ---------------------------------------------------------------------------
// GEMM: C[M,N] = A[M,K] @ W[N,K]^T  (A, W bf16 row-major, K-contiguous)
// 128x128 tile, BK=64, 4 waves (2x2 of 64x64), mfma 16x16x32 bf16.
// global_load_lds w=16 staging; XOR swizzle via pre-swizzled global source.
// Epilogue: +bias, optional ReLU, optional fp32 residual.
// OUTMODE: 0 = bf16 row-major, 1 = fp32 row-major, 2 = bf16 transposed (B,N,S)
// ---------------------------------------------------------------------------
template <bool RELU, bool RESID, int OUTMODE>
__global__ __launch_bounds__(256, 2) void gemm_nt(
    const u16* __restrict__ A, const u16* __restrict__ W,
    const float* __restrict__ bias, const float* __restrict__ resid,
    void* __restrict__ Cout, int N, int K) {
    __shared__ u16 Als[128 * 64];
    __shared__ u16 Bls[128 * 64];
    const int tid = threadIdx.x;
    const int l = tid & 63, w = tid >> 6;
    const int m0 = blockIdx.y * 128;
    const int n0 = blockIdx.x * 128;
    const int wr = (w >> 1) * 64, wc = (w & 1) * 64;
    const int lhi = l >> 4, l15 = l & 15, l7 = l & 7;

    f32x4 acc[4][4] = {};

    // staging geometry: chunk = 512 elems (64 lanes x 8); lane covers
    // row = cc*8 + (l>>3), swizzled col block ((l&7)*8) ^ ((row&7)<<3)
    const int srow = l >> 3;
    const int scol = ((l & 7) * 8) ^ (srow << 3);

    for (int kt = 0; kt < K; kt += 64) {
        __syncthreads();
#pragma unroll
        for (int i = 0; i < 4; ++i) {
            int cc = w * 4 + i;  // 0..15
            int grow = cc * 8 + srow;
            gload_lds16(&A[(size_t)(m0 + grow) * K + kt + scol], &Als[cc * 512]);
            gload_lds16(&W[(size_t)(n0 + grow) * K + kt + scol], &Bls[cc * 512]);
        }
        __syncthreads();
#pragma unroll
        for (int kk = 0; kk < 2; ++kk) {
            const int koff = (kk * 32 + lhi * 8) ^ (l7 << 3);
            bf16x8 af[4], bfr[4];
#pragma unroll
            for (int m = 0; m < 4; ++m)
                af[m] = *reinterpret_cast<const bf16x8*>(
                    &Als[(wr + m * 16 + l15) * 64 + koff]);
#pragma unroll
            for (int n = 0; n < 4; ++n)
                bfr[n] = *reinterpret_cast<const bf16x8*>(
                    &Bls[(wc + n * 16 + l15) * 64 + koff]);
#pragma unroll
            for (int m = 0; m < 4; ++m)
#pragma unroll
                for (int n = 0; n < 4; ++n)
                    acc[m][n] = __builtin_amdgcn_mfma_f32_16x16x32_bf16(
                        af[m], bfr[n], acc[m][n], 0, 0, 0);
        }
    }

    // epilogue; C/D lane map: col = l&15, row = 4*(l>>4)+r (verified m89/m91)
    int colg[4];
    float bv[4];
#pragma unroll
    for (int cn = 0; cn < 4; ++cn) {
        colg[cn] = n0 + wc + cn * 16 + l15;
        bv[cn] = bias[colg[cn]];
    }
#pragma unroll
    for (int am = 0; am < 4; ++am) {
        int rowg = m0 + wr + am * 16 + 4 * lhi;
#pragma unroll
        for (int cn = 0; cn < 4; ++cn) {
            float v[4];
#pragma unroll
            for (int r = 0; r < 4; ++r) {
                float t = acc[am][cn][r] + bv[cn];
                if constexpr (RELU) t = fmaxf(t, 0.f);
                if constexpr (RESID)
                    t += resid[(size_t)(rowg + r) * N + colg[cn]];
                v[r] = t;
            }
            if constexpr (OUTMODE == 0) {
                u16* o = (u16*)Cout;
#pragma unroll
                for (int r = 0; r < 4; ++r)
                    o[(size_t)(rowg + r) * N + colg[cn]] = f2b(v[r]);
            } else if constexpr (OUTMODE == 1) {
                float* o = (float*)Cout;
#pragma unroll
                for (int r = 0; r < 4; ++r)
                    o[(size_t)(rowg + r) * N + colg[cn]] = v[r];
            } else {
                // transposed store: out[(b*512 + col)*2048 + s], 4 consecutive
                // s per lane -> one 8B store
                u16* o = (u16*)Cout;
                int bb = rowg >> 11, sloc = rowg & 2047;
                ushort4 pk;
                pk.x = f2b(v[0]); pk.y = f2b(v[1]);
                pk.z = f2b(v[2]); pk.w = f2b(v[3]);
                *reinterpret_cast<ushort4*>(
                    &o[((size_t)(bb * 512 + colg[cn])) * 2048 + sloc]) = pk;
            }
        }
    }
}

// ---------------------------------------------------------------------------
// Flash attention fwd. q,k: (B,S,512) bf16; vT: (B,512,S) bf16; out bf16.
// Block = (q-tile of 64) x (b,h); 4 waves x 16 q-rows; KV tiles of 64.
// grid (32, 64), 256 threads.
// ---------------------------------------------------------------------------
__global__ __launch_bounds__(256, 2) void attn_fwd(
    const u16* __restrict__ q, const u16* __restrict__ k,
    const u16* __restrict__ vT, const int* __restrict__ mask,
    u16* __restrict__ out) {
    __shared__ u16 Kls[64 * 64];
    __shared__ u16 Vls[64 * 64];
    __shared__ u16 Pls[4 * 16 * 64];
    const int tid = threadIdx.x;
    const int l = tid & 63, w = tid >> 6;
    const int lhi = l >> 4, l15 = l & 15, l7 = l & 7;
    const int bh = blockIdx.y, b = bh >> 3, h = bh & 7;
    const int q0 = blockIdx.x * 64 + w * 16;

    bf16x8 qf[2];
    {
        const size_t qa = ((size_t)b * SEQ + q0 + l15) * DMODEL + h * 64 + lhi * 8;
        qf[0] = *reinterpret_cast<const bf16x8*>(&q[qa]);
        qf[1] = *reinterpret_cast<const bf16x8*>(&q[qa + 32]);
    }

    float m_r[4] = {-3e38f, -3e38f, -3e38f, -3e38f};
    float l_r[4] = {0.f, 0.f, 0.f, 0.f};
    f32x4 oacc[4] = {};

    const int srow = l >> 3;
    const int scol = ((l & 7) * 8) ^ (srow << 3);

    for (int kv = 0; kv < SEQ; kv += 64) {
        __syncthreads();
#pragma unroll
        for (int i = 0; i < 2; ++i) {
            int cc = w * 2 + i;  // 0..7
            int grow = cc * 8 + srow;
            gload_lds16(&k[((size_t)b * SEQ + kv + grow) * DMODEL + h * 64 + scol],
                        &Kls[cc * 512]);
            gload_lds16(&vT[((size_t)(b * 512) + h * 64 + grow) * SEQ + kv + scol],
                        &Vls[cc * 512]);
        }
        __syncthreads();

        // scores: D[q][key] per 16-key chunk c
        f32x4 sc[4];
#pragma unroll
        for (int c = 0; c < 4; ++c) {
            int krow = c * 16 + l15;
            bf16x8 k0 = *reinterpret_cast<const bf16x8*>(
                &Kls[krow * 64 + ((lhi * 8) ^ (l7 << 3))]);
            bf16x8 k1 = *reinterpret_cast<const bf16x8*>(
                &Kls[krow * 64 + ((32 + lhi * 8) ^ (l7 << 3))]);
            f32x4 z = {};
            z = __builtin_amdgcn_mfma_f32_16x16x32_bf16(qf[0], k0, z, 0, 0, 0);
            z = __builtin_amdgcn_mfma_f32_16x16x32_bf16(qf[1], k1, z, 0, 0, 0);
            sc[c] = z;
        }
        float mb[4];
#pragma unroll
        for (int c = 0; c < 4; ++c)
            mb[c] = (mask[b * SEQ + kv + c * 16 + l15] == 0) ? -1e9f : 0.f;
#pragma unroll
        for (int c = 0; c < 4; ++c)
#pragma unroll
            for (int r = 0; r < 4; ++r)
                sc[c][r] = sc[c][r] * 0.125f + mb[c];

        // online softmax per q-row (row r lives across the 16 lanes of a group)
        float fr[4];
#pragma unroll
        for (int r = 0; r < 4; ++r) {
            float mx = fmaxf(fmaxf(sc[0][r], sc[1][r]), fmaxf(sc[2][r], sc[3][r]));
            mx = fmaxf(mx, __shfl_xor(mx, 1, 64));
            mx = fmaxf(mx, __shfl_xor(mx, 2, 64));
            mx = fmaxf(mx, __shfl_xor(mx, 4, 64));
            mx = fmaxf(mx, __shfl_xor(mx, 8, 64));
            float mn = fmaxf(m_r[r], mx);
            fr[r] = __expf(m_r[r] - mn);
            m_r[r] = mn;
            float ps = 0.f;
#pragma unroll
            for (int c = 0; c < 4; ++c) {
                float p = __expf(sc[c][r] - mn);
                sc[c][r] = p;
                ps += p;
            }
            ps += __shfl_xor(ps, 1, 64);
            ps += __shfl_xor(ps, 2, 64);
            ps += __shfl_xor(ps, 4, 64);
            ps += __shfl_xor(ps, 8, 64);
            l_r[r] = l_r[r] * fr[r] + ps;
        }
#pragma unroll
        for (int c = 0; c < 4; ++c)
#pragma unroll
            for (int r = 0; r < 4; ++r) oacc[c][r] *= fr[r];

        // P -> per-wave LDS (swizzled), then PV
#pragma unroll
        for (int r = 0; r < 4; ++r) {
            int prow = 4 * lhi + r;
            int sw = (prow & 7) << 3;
#pragma unroll
            for (int c = 0; c < 4; ++c)
                Pls[w * 1024 + prow * 64 + ((c * 16 + l15) ^ sw)] = f2b(sc[c][r]);
        }
#pragma unroll
        for (int kk = 0; kk < 2; ++kk) {
            bf16x8 pa = *reinterpret_cast<const bf16x8*>(
                &Pls[w * 1024 + l15 * 64 + ((kk * 32 + lhi * 8) ^ (l7 << 3))]);
#pragma unroll
            for (int c = 0; c < 4; ++c) {
                bf16x8 vf = *reinterpret_cast<const bf16x8*>(
                    &Vls[(c * 16 + l15) * 64 + ((kk * 32 + lhi * 8) ^ (l7 << 3))]);
                oacc[c] = __builtin_amdgcn_mfma_f32_16x16x32_bf16(pa, vf, oacc[c],
                                                                  0, 0, 0);
            }
        }
    }

#pragma unroll
    for (int r = 0; r < 4; ++r) {
        float inv = 1.f / l_r[r];
        size_t rowa = ((size_t)b * SEQ + q0 + 4 * lhi + r) * DMODEL + h * 64;
#pragma unroll
        for (int c = 0; c < 4; ++c)
            out[rowa + c * 16 + l15] = f2b(oacc[c][r] * inv);
    }
}

// ---------------------------------------------------------------------------
extern "C" void kernel_launch(void* const* d_in, const int* in_sizes, int n_in,
                              void* d_out, int out_size, void* d_ws,
                              size_t ws_size, hipStream_t stream) {
    const float* x = (const float*)d_in[0];
    const int* mask = (const int*)d_in[1];
    const float* w_q = (const float*)d_in[2];
    const float* b_q = (const float*)d_in[3];
    const float* w_k = (const float*)d_in[4];
    const float* b_k = (const float*)d_in[5];
    const float* w_v = (const float*)d_in[6];
    const float* b_v = (const float*)d_in[7];
    const float* w_o = (const float*)d_in[8];
    const float* b_o = (const float*)d_in[9];
    const float* w_1 = (const float*)d_in[10];
    const float* b_1 = (const float*)d_in[11];
    const float* w_2 = (const float*)d_in[12];
    const float* b_2 = (const float*)d_in[13];

    char* ws = (char*)d_ws;
    const size_t MB = 1024ull * 1024ull;
    u16* lnx = (u16*)(ws + 0);          // 16 MiB; reused as attn_out
    u16* qb = (u16*)(ws + 16 * MB);     // 16 MiB; reused as lnx1
    u16* kb = (u16*)(ws + 32 * MB);     // 16 MiB
    u16* vT = (u16*)(ws + 48 * MB);     // 16 MiB
    u16* lnx1 = (u16*)(ws + 16 * MB);   // after attn, q dead
    u16* hbuf = (u16*)(ws + 32 * MB);   // 64 MiB [32,96); k,vT dead
    u16* wqb = (u16*)(ws + 96 * MB);
    u16* wkb = wqb + 262144;
    u16* wvb = wqb + 2 * 262144;
    u16* wob = wqb + 3 * 262144;
    u16* w1b = wqb + 4 * 262144;
    u16* w2b = w1b + 1048576;
    u16* attn_o = lnx;
    float* x1 = (float*)d_out;  // x1 lives in d_out (single-owner in-place)

    cast_weights<<<1536, 256, 0, stream>>>(w_q, w_k, w_v, w_o, w_1, w_2, wqb,
                                           wkb, wvb, wob, w1b, w2b);
    ln_rows<<<4096, 256, 0, stream>>>(x, lnx);

    dim3 g4(4, 128), g16(16, 128);
    gemm_nt<false, false, 0><<<g4, 256, 0, stream>>>(lnx, wqb, b_q, nullptr,
                                                     qb, 512, 512);
    gemm_nt<false, false, 0><<<g4, 256, 0, stream>>>(lnx, wkb, b_k, nullptr,
                                                     kb, 512, 512);
    gemm_nt<false, false, 2><<<g4, 256, 0, stream>>>(lnx, wvb, b_v, nullptr,
                                                     vT, 512, 512);
    attn_fwd<<<dim3(32, 64), 256, 0, stream>>>(qb, kb, vT, mask, attn_o);
    gemm_nt<false, true, 1><<<g4, 256, 0, stream>>>(attn_o, wob, b_o, x, x1,
                                                    512, 512);
    ln_rows<<<4096, 256, 0, stream>>>(x1, lnx1);
    gemm_nt<true, false, 0><<<g16, 256, 0, stream>>>(lnx1, w1b, b_1, nullptr,
                                                     hbuf, 2048, 512);
    gemm_nt<false, true, 1><<<g4, 256, 0, stream>>>(hbuf, w2b, b_2, x1,
                                                    (float*)d_out, 512, 2048);
}